// Round 7
// baseline (113.938 us; speedup 1.0000x reference)
//
#include <hip/hip_runtime.h>
#include <stdint.h>

#define N_ROWS 65536
#define K_CODES 1024
#define D 64
#define OUT_ELEMS 4194304
#define LOSS_SCALE (1.25f / 4194304.0f)
#define ROWS_PER_BLOCK 128
#define GRID_DIST (N_ROWS / ROWS_PER_BLOCK)  // 512 blocks = 2/CU

typedef short short8 __attribute__((ext_vector_type(8)));
typedef float f32x4 __attribute__((ext_vector_type(4)));

__device__ __forceinline__ unsigned short f2bf(float f) {
    unsigned int u = __float_as_uint(f);
    return (unsigned short)((u + 0x7fffu + ((u >> 16) & 1u)) >> 16);  // RNE
}
__device__ __forceinline__ short8 pack8(float4 a, float4 b) {
    short8 r;
    r[0] = f2bf(a.x); r[1] = f2bf(a.y); r[2] = f2bf(a.z); r[3] = f2bf(a.w);
    r[4] = f2bf(b.x); r[5] = f2bf(b.y); r[6] = f2bf(b.z); r[7] = f2bf(b.w);
    return r;
}

// Single fused kernel. Dataflow inversion vs R1-R6: codebook is STATIONARY in
// VGPRs (wave w owns codes [w*256,w*256+256) as 16 B-frag tiles, loaded+converted
// once), z streams through as A-frags straight from global (no LDS staging).
// Each 16-row set: 32 MFMAs (16 indep 2-chains) per wave, argmin via packed u32
// keys (trunc dist | 10-bit code id -> numpy first-min ties), cross-wave combine
// through 512B LDS, coalesced quantize-write + loss in the combine phase.
__global__ __launch_bounds__(256, 2) void vq_kernel(
        const float* __restrict__ z, const float* __restrict__ emb,
        float* __restrict__ out, float* __restrict__ partials) {
    const int tid = threadIdx.x;
    const int w = tid >> 6, lane = tid & 63;
    const int n = lane & 15, q = lane >> 4;
    __shared__ unsigned int sh_key[2][4][16];  // [set parity][wave][row]
    __shared__ float ps[4];

    const int r0 = blockIdx.x * ROWS_PER_BLOCK;

    // --- z set 0 loads first (codebook conversion VALU below hides their latency)
    float4 c0, c1, c2, c3;
    {
        const float* zr = z + (size_t)(r0 + n) * D + q * 8;
        c0 = *(const float4*)(zr);      c1 = *(const float4*)(zr + 4);
        c2 = *(const float4*)(zr + 32); c3 = *(const float4*)(zr + 36);
    }

    // --- Stationary codebook: 16 tiles x (2 short8 B-frags) + e2+1 scalars.
    // B-frag lane layout: code = lane&15, dims = q*8..+8 (and +32 for K-half 1).
    // Values pre-scaled by -2 so MFMA acc = e2+1 - 2 z.e directly.
    const int cbase = w * 256 + n;
    short8 cb0[16], cb1[16];
    float e2w[16];
#pragma unroll
    for (int ct = 0; ct < 16; ct++) {
        const float* er = emb + (size_t)(cbase + ct * 16) * D + q * 8;
        float4 g0 = *(const float4*)(er);      float4 g1 = *(const float4*)(er + 4);
        float4 g2 = *(const float4*)(er + 32); float4 g3 = *(const float4*)(er + 36);
        float e2p = g0.x*g0.x + g0.y*g0.y + g0.z*g0.z + g0.w*g0.w
                  + g1.x*g1.x + g1.y*g1.y + g1.z*g1.z + g1.w*g1.w
                  + g2.x*g2.x + g2.y*g2.y + g2.z*g2.z + g2.w*g2.w
                  + g3.x*g3.x + g3.y*g3.y + g3.z*g3.z + g3.w*g3.w;
        e2p += __shfl_xor(e2p, 16, 64);
        e2p += __shfl_xor(e2p, 32, 64);      // exact fp32 ||e||^2, full dim
        e2w[ct] = e2p + 1.0f;
        float4 m0 = {-2.f*g0.x, -2.f*g0.y, -2.f*g0.z, -2.f*g0.w};
        float4 m1 = {-2.f*g1.x, -2.f*g1.y, -2.f*g1.z, -2.f*g1.w};
        float4 m2 = {-2.f*g2.x, -2.f*g2.y, -2.f*g2.z, -2.f*g2.w};
        float4 m3 = {-2.f*g3.x, -2.f*g3.y, -2.f*g3.z, -2.f*g3.w};
        cb0[ct] = pack8(m0, m1);
        cb1[ct] = pack8(m2, m3);
    }

    float lossacc = 0.f;
    const float4* emb4 = (const float4*)emb;
    float4* o4 = (float4*)out;

    for (int s = 0; s < 8; s++) {
        // ||z||^2 (exact fp32; identical instruction sequence in every wave ->
        // bitwise identical -> keys comparable across waves).
        float z2p = c0.x*c0.x + c0.y*c0.y + c0.z*c0.z + c0.w*c0.w
                  + c1.x*c1.x + c1.y*c1.y + c1.z*c1.z + c1.w*c1.w
                  + c2.x*c2.x + c2.y*c2.y + c2.z*c2.z + c2.w*c2.w
                  + c3.x*c3.x + c3.y*c3.y + c3.z*c3.z + c3.w*c3.w;
        z2p += __shfl_xor(z2p, 16, 64);
        z2p += __shfl_xor(z2p, 32, 64);      // z2 of row s*16+n, all lanes with this n
        float z2r[4];
#pragma unroll
        for (int r = 0; r < 4; r++) z2r[r] = __shfl(z2p, q * 4 + r, 64);  // rows q*4+r

        short8 alo = pack8(c0, c1), ahi = pack8(c2, c3);  // A-frag: row=lane&15, k=q*8+j

        unsigned int best[4] = {~0u, ~0u, ~0u, ~0u};
#pragma unroll
        for (int ct = 0; ct < 16; ct++) {
            f32x4 acc = {e2w[ct], e2w[ct], e2w[ct], e2w[ct]};
            acc = __builtin_amdgcn_mfma_f32_16x16x32_bf16(alo, cb0[ct], acc, 0, 0, 0);
            acc = __builtin_amdgcn_mfma_f32_16x16x32_bf16(ahi, cb1[ct], acc, 0, 0, 0);
            const unsigned int id = (unsigned int)(cbase + ct * 16);  // this lane's code
#pragma unroll
            for (int r = 0; r < 4; r++) {
                // dist_pos = e2 - 2z.e + z2 + 1 > 0; trunc keeps order, low 10b = code
                unsigned int key = (__float_as_uint(acc[r] + z2r[r]) & 0xFFFFFC00u) | id;
                best[r] = best[r] < key ? best[r] : key;
            }
        }
        // min over this wave's 16 code-columns (lanes n within each quad)
#pragma unroll
        for (int r = 0; r < 4; r++) {
#pragma unroll
            for (int x = 1; x < 16; x <<= 1) {
                unsigned int o = (unsigned int)__shfl_xor((int)best[r], x, 64);
                best[r] = o < best[r] ? o : best[r];
            }
        }
        if (n == 0)  // lane (0,q) holds rows q*4..q*4+3
            *(uint4*)&sh_key[s & 1][w][q << 2] =
                make_uint4(best[0], best[1], best[2], best[3]);

        // prefetch next set's z before the barrier (latency hidden by combine)
        float4 n0, n1, n2, n3;
        if (s < 7) {
            const float* zr = z + (size_t)(r0 + (s + 1) * 16 + n) * D + q * 8;
            n0 = *(const float4*)(zr);      n1 = *(const float4*)(zr + 4);
            n2 = *(const float4*)(zr + 32); n3 = *(const float4*)(zr + 36);
        }
        __syncthreads();

        // combine: 256 threads = 16 rows x 16 float4-units; coalesced write
        {
            const int row = tid >> 4, unit = tid & 15;
            unsigned int k0 = sh_key[s & 1][0][row], k1 = sh_key[s & 1][1][row];
            unsigned int k2 = sh_key[s & 1][2][row], k3 = sh_key[s & 1][3][row];
            unsigned int ka = k0 < k1 ? k0 : k1, kb = k2 < k3 ? k2 : k3;
            unsigned int km = ka < kb ? ka : kb;
            int idx = (int)(km & 1023u);
            o4[(size_t)(r0 + s * 16 + row) * 16 + unit] = emb4[idx * 16 + unit];
            if (unit == 0)  // one thread per row: ||q-z||^2 = key_float - 1
                lossacc += __uint_as_float(km & 0xFFFFFC00u) - 1.0f;
        }
        c0 = n0; c1 = n1; c2 = n2; c3 = n3;
    }

    // block loss partial (each row counted exactly once)
#pragma unroll
    for (int off = 32; off > 0; off >>= 1)
        lossacc += __shfl_down(lossacc, off, 64);
    if (lane == 0) ps[w] = lossacc;
    __syncthreads();
    if (tid == 0) partials[blockIdx.x] = ps[0] + ps[1] + ps[2] + ps[3];
}

// Single block: sum 512 partials -> loss (no atomics anywhere).
__global__ __launch_bounds__(256) void loss_kernel(const float* __restrict__ partials,
                                                   float* __restrict__ loss) {
    float s = partials[threadIdx.x] + partials[threadIdx.x + 256];
#pragma unroll
    for (int off = 32; off > 0; off >>= 1)
        s += __shfl_down(s, off, 64);
    __shared__ float ps[4];
    int wave = threadIdx.x >> 6, lane = threadIdx.x & 63;
    if (lane == 0) ps[wave] = s;
    __syncthreads();
    if (threadIdx.x == 0) loss[0] = (ps[0] + ps[1] + ps[2] + ps[3]) * LOSS_SCALE;
}

extern "C" void kernel_launch(void* const* d_in, const int* in_sizes, int n_in,
                              void* d_out, int out_size, void* d_ws, size_t ws_size,
                              hipStream_t stream) {
    const float* z = (const float*)d_in[0];
    const float* emb = (const float*)d_in[1];
    float* out = (float*)d_out;
    float* loss = out + OUT_ELEMS;
    float* partials = (float*)d_ws;  // 2 KiB

    vq_kernel<<<GRID_DIST, 256, 0, stream>>>(z, emb, out, partials);
    loss_kernel<<<1, 256, 0, stream>>>(partials, loss);
}

// Round 8
// 100.151 us; speedup vs baseline: 1.1377x; 1.1377x over previous
//
#include <hip/hip_runtime.h>
#include <stdint.h>

#define N_ROWS 65536
#define K_CODES 1024
#define D 64
#define OUT_ELEMS 4194304
#define LOSS_SCALE (1.25f / 4194304.0f)
#define ROWS_PER_BLOCK 256
#define GRID_DIST (N_ROWS / ROWS_PER_BLOCK)  // 256 blocks = 1/CU
#define SETS (ROWS_PER_BLOCK / 16)           // 16 sets of 16 rows

typedef short short8 __attribute__((ext_vector_type(8)));
typedef float f32x4 __attribute__((ext_vector_type(4)));

__device__ __forceinline__ unsigned short f2bf(float f) {
    unsigned int u = __float_as_uint(f);
    return (unsigned short)((u + 0x7fffu + ((u >> 16) & 1u)) >> 16);  // RNE
}
__device__ __forceinline__ short8 pack8(float4 a, float4 b) {
    short8 r;
    r[0] = f2bf(a.x); r[1] = f2bf(a.y); r[2] = f2bf(a.z); r[3] = f2bf(a.w);
    r[4] = f2bf(b.x); r[5] = f2bf(b.y); r[6] = f2bf(b.z); r[7] = f2bf(b.w);
    return r;
}

// Code-stationary VQ, spill-free edition. 512-thread blocks: 8 waves each own
// 128 codes as 8 B-frag tiles in VGPRs (64 regs, loaded+converted once).
// z streams straight from global as A-frags (L1/L2-hot: all 8 waves read the
// same 64KB row slice). Per 16-row set: 16 MFMAs/wave (8 indep 2-chains),
// packed-key argmin (trunc dist | 10-bit code -> numpy first-min), cross-wave
// combine via 1KB LDS keys (double-buffered, 1 barrier/set), coalesced
// quantize-write + loss in combine. No LDS staging, no global_load_lds, no
// vmcnt poisoning, no spill.
__global__ __launch_bounds__(512, 2) void vq_kernel(
        const float* __restrict__ z, const float* __restrict__ emb,
        float* __restrict__ out, float* __restrict__ partials) {
    const int tid = threadIdx.x;
    const int w = tid >> 6, lane = tid & 63;
    const int n = lane & 15, q = lane >> 4;
    __shared__ unsigned int sh_key[2][8][16];  // [set parity][wave][row]
    __shared__ float ps[8];

    const int r0 = blockIdx.x * ROWS_PER_BLOCK;

    // --- z set 0 loads first (codebook conversion VALU hides their latency)
    float4 c0, c1, c2, c3;
    {
        const float* zr = z + (size_t)(r0 + n) * D + q * 8;
        c0 = *(const float4*)(zr);      c1 = *(const float4*)(zr + 4);
        c2 = *(const float4*)(zr + 32); c3 = *(const float4*)(zr + 36);
    }

    // --- Stationary codebook: wave w owns codes [w*128, w*128+128) as 8 tiles.
    // B-frag layout: code = lane&15, dims q*8..+8 (+32 for K-half 1); values
    // pre-scaled by -2 so MFMA acc = e2+1 - 2 z.e directly. e2 exact fp32.
    const int cbase = w * 128 + n;
    short8 cb0[8], cb1[8];
    float e2w[8];
#pragma unroll
    for (int ct = 0; ct < 8; ct++) {
        const float* er = emb + (size_t)(cbase + ct * 16) * D + q * 8;
        float4 g0 = *(const float4*)(er);      float4 g1 = *(const float4*)(er + 4);
        float4 g2 = *(const float4*)(er + 32); float4 g3 = *(const float4*)(er + 36);
        float e2p = g0.x*g0.x + g0.y*g0.y + g0.z*g0.z + g0.w*g0.w
                  + g1.x*g1.x + g1.y*g1.y + g1.z*g1.z + g1.w*g1.w
                  + g2.x*g2.x + g2.y*g2.y + g2.z*g2.z + g2.w*g2.w
                  + g3.x*g3.x + g3.y*g3.y + g3.z*g3.z + g3.w*g3.w;
        e2p += __shfl_xor(e2p, 16, 64);
        e2p += __shfl_xor(e2p, 32, 64);      // exact fp32 ||e||^2 over all 64 dims
        e2w[ct] = e2p + 1.0f;
        float4 m0 = {-2.f*g0.x, -2.f*g0.y, -2.f*g0.z, -2.f*g0.w};
        float4 m1 = {-2.f*g1.x, -2.f*g1.y, -2.f*g1.z, -2.f*g1.w};
        float4 m2 = {-2.f*g2.x, -2.f*g2.y, -2.f*g2.z, -2.f*g2.w};
        float4 m3 = {-2.f*g3.x, -2.f*g3.y, -2.f*g3.z, -2.f*g3.w};
        cb0[ct] = pack8(m0, m1);
        cb1[ct] = pack8(m2, m3);
    }

    float lossacc = 0.f;
    const float4* emb4 = (const float4*)emb;
    float4* o4 = (float4*)out;

    for (int s = 0; s < SETS; s++) {
        // ||z||^2: identical instruction sequence + inputs in every wave ->
        // bitwise identical -> keys comparable across waves.
        float z2p = c0.x*c0.x + c0.y*c0.y + c0.z*c0.z + c0.w*c0.w
                  + c1.x*c1.x + c1.y*c1.y + c1.z*c1.z + c1.w*c1.w
                  + c2.x*c2.x + c2.y*c2.y + c2.z*c2.z + c2.w*c2.w
                  + c3.x*c3.x + c3.y*c3.y + c3.z*c3.z + c3.w*c3.w;
        z2p += __shfl_xor(z2p, 16, 64);
        z2p += __shfl_xor(z2p, 32, 64);      // z2 of row s*16+n
        float z2r[4];
#pragma unroll
        for (int r = 0; r < 4; r++) z2r[r] = __shfl(z2p, q * 4 + r, 64);  // row q*4+r

        short8 alo = pack8(c0, c1), ahi = pack8(c2, c3);  // A: row=lane&15, k=q*8+j

        unsigned int best[4] = {~0u, ~0u, ~0u, ~0u};
#pragma unroll
        for (int ct = 0; ct < 8; ct++) {
            f32x4 acc = {e2w[ct], e2w[ct], e2w[ct], e2w[ct]};
            acc = __builtin_amdgcn_mfma_f32_16x16x32_bf16(alo, cb0[ct], acc, 0, 0, 0);
            acc = __builtin_amdgcn_mfma_f32_16x16x32_bf16(ahi, cb1[ct], acc, 0, 0, 0);
            const unsigned int id = (unsigned int)(cbase + ct * 16);  // lane's code
#pragma unroll
            for (int r = 0; r < 4; r++) {
                // dist_pos = e2 - 2z.e + z2 + 1 > 0; trunc keeps order, low10 = code
                unsigned int key = (__float_as_uint(acc[r] + z2r[r]) & 0xFFFFFC00u) | id;
                best[r] = best[r] < key ? best[r] : key;
            }
        }
        // min over this wave's 16 code-columns
#pragma unroll
        for (int r = 0; r < 4; r++) {
#pragma unroll
            for (int x = 1; x < 16; x <<= 1) {
                unsigned int o = (unsigned int)__shfl_xor((int)best[r], x, 64);
                best[r] = o < best[r] ? o : best[r];
            }
        }
        if (n == 0)  // lane (0,q) holds rows q*4..q*4+3
            *(uint4*)&sh_key[s & 1][w][q << 2] =
                make_uint4(best[0], best[1], best[2], best[3]);

        // prefetch next set's z before the barrier (combine hides its latency)
        float4 n0, n1, n2, n3;
        if (s < SETS - 1) {
            const float* zr = z + (size_t)(r0 + (s + 1) * 16 + n) * D + q * 8;
            n0 = *(const float4*)(zr);      n1 = *(const float4*)(zr + 4);
            n2 = *(const float4*)(zr + 32); n3 = *(const float4*)(zr + 36);
        }
        __syncthreads();

        // combine (first 4 waves): 256 threads = 16 rows x 16 float4 units
        if (tid < 256) {
            const int row = tid >> 4, unit = tid & 15;
            unsigned int km = sh_key[s & 1][0][row];
#pragma unroll
            for (int ww = 1; ww < 8; ww++) {
                unsigned int o = sh_key[s & 1][ww][row];
                km = o < km ? o : km;
            }
            int idx = (int)(km & 1023u);
            o4[(size_t)(r0 + s * 16 + row) * 16 + unit] = emb4[idx * 16 + unit];
            if (unit == 0)  // one thread per row: ||q-z||^2 = key_float - 1
                lossacc += __uint_as_float(km & 0xFFFFFC00u) - 1.0f;
        }
        c0 = n0; c1 = n1; c2 = n2; c3 = n3;
    }

    // block loss partial (each row counted exactly once; waves 4-7 contribute 0)
#pragma unroll
    for (int off = 32; off > 0; off >>= 1)
        lossacc += __shfl_down(lossacc, off, 64);
    if (lane == 0) ps[w] = lossacc;
    __syncthreads();
    if (tid == 0) {
        float s8 = 0.f;
#pragma unroll
        for (int ww = 0; ww < 8; ww++) s8 += ps[ww];
        partials[blockIdx.x] = s8;
    }
}

// Single block: sum 256 partials -> loss (no atomics anywhere).
__global__ __launch_bounds__(256) void loss_kernel(const float* __restrict__ partials,
                                                   float* __restrict__ loss) {
    float s = partials[threadIdx.x];
#pragma unroll
    for (int off = 32; off > 0; off >>= 1)
        s += __shfl_down(s, off, 64);
    __shared__ float ps[4];
    int wave = threadIdx.x >> 6, lane = threadIdx.x & 63;
    if (lane == 0) ps[wave] = s;
    __syncthreads();
    if (threadIdx.x == 0) loss[0] = (ps[0] + ps[1] + ps[2] + ps[3]) * LOSS_SCALE;
}

extern "C" void kernel_launch(void* const* d_in, const int* in_sizes, int n_in,
                              void* d_out, int out_size, void* d_ws, size_t ws_size,
                              hipStream_t stream) {
    const float* z = (const float*)d_in[0];
    const float* emb = (const float*)d_in[1];
    float* out = (float*)d_out;
    float* loss = out + OUT_ELEMS;
    float* partials = (float*)d_ws;  // 1 KiB

    vq_kernel<<<GRID_DIST, 512, 0, stream>>>(z, emb, out, partials);
    loss_kernel<<<1, 256, 0, stream>>>(partials, loss);
}